// Round 4
// baseline (238.288 us; speedup 1.0000x reference)
//
#include <hip/hip_runtime.h>
#include <cstdint>
#include <cstddef>

// B=8, N=2048, C=512
// out = feature + softmax(Q K^T) @ V / sqrt(C),  Q = X Wq^T + bq etc.
// R14: fixes R13's DMA race. R13 issued ds_reads of tile kt BEFORE the
//      vmcnt that guaranteed T(kt)'s global_load_lds data had landed
//      (DS pipe and VMEM->LDS DMA are unordered) -> stale reads, absmax
//      0.19. Phase reordered to: stage T(kt+1) -> VMW(4) [T(kt) done] ->
//      SBAR -> ds_reads -> lgkm0 -> MFMA -> SBAR. The lgkm latency now
//      sits inside the phase; the 4-blocks/CU TLP (R13's design goal:
//      128x128 tile, BK=32, 4 waves, 32KB LDS) is what covers it.
//      FIFO re-enumerated: prologue stages T0,T1 (no wait); phase 0 VMW(4)
//      => T0 done; steady: stage T(kt+1), outstanding<=8, VMW(4) => T(kt)
//      done; tail VMW(0). WAR: T(kt+1) overwrites T(kt-1)'s slot, read-
//      drained (lgkm0) before phase(kt-1)'s closing SBAR. ✓
// prep / gemm_qkv unchanged.

typedef __bf16 bf16x8 __attribute__((ext_vector_type(8)));
typedef float f32x4 __attribute__((ext_vector_type(4)));
typedef short short4v __attribute__((ext_vector_type(4)));

__device__ __forceinline__ short f2b(float f) {
  union { float f; unsigned u; } u; u.f = f;
  unsigned r = (u.u + 0x7fffu + ((u.u >> 16) & 1u)) >> 16;  // RNE
  return (short)r;
}

#define GLDS(gptr, lptr) \
  __builtin_amdgcn_global_load_lds( \
      (const __attribute__((address_space(1))) unsigned int*)(const void*)(gptr), \
      (__attribute__((address_space(3))) unsigned int*)(void*)(lptr), 16, 0, 0)

// plain fragment load from [rows][64] XOR-swizzled LDS (gemm_qkv only).
__device__ __forceinline__ bf16x8 ldfrag64(const short* buf, int row, int kq) {
  return *(const bf16x8*)(buf + row * 64 + ((kq ^ (row & 7)) * 8));
}

// asm fragment load from [rows][32] BK=32 swizzled LDS buffer.
// Invisible to SIInsertWaitcnts -> no auto vmcnt(0) drain; completion is
// ONLY guaranteed by the explicit lgkmcnt(0) that follows.
__device__ __forceinline__ bf16x8 ldfrag32(const short* buf, int row, int l4) {
  const short* p = buf + row * 32 + ((l4 ^ ((row >> 1) & 3)) * 8);
  bf16x8 r;
  asm volatile("ds_read_b128 %0, %1"
               : "=v"(r)
               : "v"((const __attribute__((address_space(3))) short*)(const void*)p));
  return r;
}

#define LGKM0_SB() do { \
    asm volatile("s_waitcnt lgkmcnt(0)" ::: "memory"); \
    __builtin_amdgcn_sched_barrier(0); } while (0)
#define VMW(n) asm volatile("s_waitcnt vmcnt(" #n ")" ::: "memory")
#define SBAR() __builtin_amdgcn_s_barrier()
#define PRIO1() __builtin_amdgcn_s_setprio(1)
#define PRIO0() __builtin_amdgcn_s_setprio(0)

// ---------------- merged prep: feature->bf16, weights->bf16, bias pack, l=0 ----------------
__global__ __launch_bounds__(256) void prep(const float* __restrict__ f,
                                            const float* __restrict__ w0,
                                            const float* __restrict__ w1,
                                            const float* __restrict__ w2,
                                            const float* __restrict__ b0,
                                            const float* __restrict__ b1,
                                            const float* __restrict__ b2,
                                            short* __restrict__ Xb, short* __restrict__ Wb,
                                            float* __restrict__ biasP, float* __restrict__ l) {
  const int bid = blockIdx.x;
  const int t = threadIdx.x;
  if (bid < 8192) {                       // feature: 2097152 float4
    int i = bid * 256 + t;
    float4 v = ((const float4*)f)[i];
    short4v o = { f2b(v.x), f2b(v.y), f2b(v.z), f2b(v.w) };
    *(short4v*)(Xb + (size_t)i * 4) = o;
  } else if (bid < 8960) {                // weights: 196608 float4
    int i = (bid - 8192) * 256 + t;
    const float* src = (i < 65536) ? w0 : (i < 131072) ? w1 : w2;
    float4 v = ((const float4*)src)[i & 65535];
    short4v o = { f2b(v.x), f2b(v.y), f2b(v.z), f2b(v.w) };
    *(short4v*)(Wb + (size_t)i * 4) = o;
  } else {                                // 8 blocks: l zero (16384 f32) + bias (1536)
    int i = (bid - 8960) * 256 + t;       // 0..2047
    float4 z = { 0.f, 0.f, 0.f, 0.f };
    ((float4*)l)[i * 2] = z;
    ((float4*)l)[i * 2 + 1] = z;
    if (i < 1536) {
      const float* s = (i < 512) ? b0 : (i < 1024) ? b1 : b2;
      biasP[i] = s[i & 511];
    }
  }
}

// ---------------- fused QKV projection: 128x128 tile, BK=64 swizzled, 16x16x32 ----------------
__global__ __launch_bounds__(256) void gemm_qkv(const short* __restrict__ X,
                                                const short* __restrict__ Wall,
                                                const float* __restrict__ biasP,
                                                short* __restrict__ Out,
                                                short* __restrict__ VtOut) {
  __shared__ __align__(16) short Xs[128 * 64];
  __shared__ __align__(16) short Ws[128 * 64];
  const int z = blockIdx.z;
  const short* Wm = Wall + (size_t)z * 262144;
  const int m0 = blockIdx.y * 128, n0 = blockIdx.x * 128;
  const int t = threadIdx.x;
  const int lane = t & 63, w = t >> 6;
  const int wn = (w & 1) * 64, wm = (w >> 1) * 64;
  const int fr = lane & 15, l4 = lane >> 4;

  f32x4 acc[4][4] = {};

  for (int k0 = 0; k0 < 512; k0 += 64) {
    __syncthreads();
#pragma unroll
    for (int u = 0; u < 4; ++u) {
      int cc = t + u * 256;
      int r = cc >> 3, cs = cc & 7;
      int kk = ((cs ^ (r & 7)) * 8);
      GLDS(X + (size_t)(m0 + r) * 512 + k0 + kk, Xs + cc * 8);
      GLDS(Wm + (size_t)(n0 + r) * 512 + k0 + kk, Ws + cc * 8);
    }
    __syncthreads();
#pragma unroll
    for (int h = 0; h < 2; ++h) {
      bf16x8 wf[4], xf[4];
#pragma unroll
      for (int i = 0; i < 4; ++i) wf[i] = ldfrag64(Ws, wn + i * 16 + fr, h * 4 + l4);
#pragma unroll
      for (int j = 0; j < 4; ++j) xf[j] = ldfrag64(Xs, wm + j * 16 + fr, h * 4 + l4);
      if (z < 2) {
#pragma unroll
        for (int i = 0; i < 4; ++i)
#pragma unroll
          for (int j = 0; j < 4; ++j)
            acc[i][j] = __builtin_amdgcn_mfma_f32_16x16x32_bf16(wf[i], xf[j], acc[i][j], 0, 0, 0);
      } else {
#pragma unroll
        for (int i = 0; i < 4; ++i)
#pragma unroll
          for (int j = 0; j < 4; ++j)
            acc[i][j] = __builtin_amdgcn_mfma_f32_16x16x32_bf16(xf[i], wf[j], acc[i][j], 0, 0, 0);
      }
    }
  }

  const int rq = l4 * 4;
  if (z < 2) {
#pragma unroll
    for (int i = 0; i < 4; ++i) {
      int nb = n0 + wn + i * 16 + rq;
      float4 bs = *(const float4*)(biasP + z * 512 + nb);
#pragma unroll
      for (int j = 0; j < 4; ++j) {
        int m = m0 + wm + j * 16 + fr;
        short4v o = { f2b(acc[i][j][0] + bs.x), f2b(acc[i][j][1] + bs.y),
                      f2b(acc[i][j][2] + bs.z), f2b(acc[i][j][3] + bs.w) };
        *(short4v*)(Out + (size_t)z * 8388608 + (size_t)m * 512 + nb) = o;
      }
    }
  } else {
    const int zB = blockIdx.y >> 4;
    const int mb = m0 & 2047;
#pragma unroll
    for (int j = 0; j < 4; ++j) {
      int d = n0 + wn + j * 16 + fr;
      float bd = biasP[1024 + d];
#pragma unroll
      for (int i = 0; i < 4; ++i) {
        int mloc = mb + wm + i * 16 + rq;
        short4v o = { f2b(acc[i][j][0] + bd), f2b(acc[i][j][1] + bd),
                      f2b(acc[i][j][2] + bd), f2b(acc[i][j][3] + bd) };
        *(short4v*)(VtOut + (size_t)zB * 1048576 + (size_t)d * 2048 + mloc) = o;
      }
    }
  }
}

// ---------------- QK^T: 128x128 tile, BK=32, 4 waves, ~4 blocks/CU ----------------
// A = K rows (keys), B = Q rows (queries). Waves 2(A)x2(B), per-wave 64x64.
// Phase kt: stage T(kt+1)->buf[c^1]; VMW(4) [=> T(kt) landed]; SBAR;
//           8 asm ds_reads of buf[c]; lgkm0; 16 MFMA; SBAR.
__global__ __launch_bounds__(256) void gemm_qk8(const short* __restrict__ Q,
                                                const short* __restrict__ Kb,
                                                short* __restrict__ P,
                                                float* __restrict__ l) {
  __shared__ __align__(16) short As[2][4096];  // keys   128x32 per buffer
  __shared__ __align__(16) short Bs[2][4096];  // queries
  // XCD remap: one batch z per XCD (Q_z+K_z = 4MB = one L2). 2048 = 8*256.
  const int id = blockIdx.x + blockIdx.y * 16 + blockIdx.z * 256;
  const int swz = (id & 7) * 256 + (id >> 3);
  const int z = swz >> 8;
  const int m0 = (swz & 15) * 128;         // keys
  const int n0 = ((swz >> 4) & 15) * 128;  // queries
  const short* __restrict__ A = Kb + (size_t)z * 1048576;
  const short* __restrict__ B = Q + (size_t)z * 1048576;
  const int t = threadIdx.x;
  const int lane = t & 63, w = t >> 6;
  const int aw = (w >> 1) * 64, bw = (w & 1) * 64;
  const int fr = lane & 15, l4 = lane >> 4;
  // staging: thread t covers chunk t (rows 0..63) and t+256 (rows 64..127)
  const int r0 = t >> 2, cs = t & 3;
  const int csw = (cs ^ ((r0 >> 1) & 3)) * 8;  // same swizzle for row r0+64
  const short* pA = A + (size_t)(m0 + r0) * 512 + csw;
  const short* pB = B + (size_t)(n0 + r0) * 512 + csw;

#define QK_STG(buf, kt) do { \
    GLDS(pA + (kt) * 32, &As[(buf)][t * 8]); \
    GLDS(pA + 64 * 512 + (kt) * 32, &As[(buf)][2048 + t * 8]); \
    GLDS(pB + (kt) * 32, &Bs[(buf)][t * 8]); \
    GLDS(pB + 64 * 512 + (kt) * 32, &Bs[(buf)][2048 + t * 8]); \
  } while (0)

  f32x4 acc[4][4] = {};
  bf16x8 a[4], b[4];

  QK_STG(0, 0); QK_STG(1, 1);   // T0, T1 in flight (8 loads)

#pragma unroll 1
  for (int kt = 0; kt < 16; ++kt) {
    const int c = kt & 1;
    if (kt >= 1 && kt < 15) QK_STG(c ^ 1, kt + 1);
    if (kt < 15) { VMW(4); } else { VMW(0); }   // T(kt) landed in LDS
    SBAR();
#pragma unroll
    for (int i = 0; i < 4; ++i) a[i] = ldfrag32(&As[c][0], aw + i * 16 + fr, l4);
#pragma unroll
    for (int n = 0; n < 4; ++n) b[n] = ldfrag32(&Bs[c][0], bw + n * 16 + fr, l4);
    LGKM0_SB(); PRIO1();
#pragma unroll
    for (int i = 0; i < 4; ++i)
#pragma unroll
      for (int n = 0; n < 4; ++n)
        acc[i][n] = __builtin_amdgcn_mfma_f32_16x16x32_bf16(a[i], b[n], acc[i][n], 0, 0, 0);
    PRIO0(); SBAR();
  }
#undef QK_STG

  // epilogue: e = exp(score), store bf16 P[query][key], row-sum atomics.
  const float LOG2E = 1.4426950408889634f;
  float rs[4] = { 0.f, 0.f, 0.f, 0.f };
#pragma unroll
  for (int i = 0; i < 4; ++i) {
    const int key = m0 + aw + i * 16 + l4 * 4;
#pragma unroll
    for (int n = 0; n < 4; ++n) {
      const int q = n0 + bw + n * 16 + fr;
      short4v o;
      float part = 0.f;
#pragma unroll
      for (int r = 0; r < 4; ++r) {
        float e = exp2f(acc[i][n][r] * LOG2E);
        o[r] = f2b(e);
        part += e;
      }
      *(short4v*)(P + (size_t)z * 4194304 + (size_t)q * 2048 + key) = o;
      rs[n] += part;
    }
  }
#pragma unroll
  for (int n = 0; n < 4; ++n) {
    rs[n] += __shfl_xor(rs[n], 16);
    rs[n] += __shfl_xor(rs[n], 32);
  }
  if (l4 == 0) {
#pragma unroll
    for (int n = 0; n < 4; ++n)
      atomicAdd(&l[z * 2048 + n0 + bw + n * 16 + fr], rs[n]);
  }
}

// ---------------- PV: 128(d) x 128(q) tile, BK=32, 4 waves, K=2048 ----------------
// A = Vt rows (d), B = P rows (queries). Same template as gemm_qk8; NT=64.
__global__ __launch_bounds__(256) void gemm_pv8(const short* __restrict__ Pm,
                                                const short* __restrict__ Vt,
                                                const float* __restrict__ l,
                                                const float* __restrict__ resid,
                                                float* __restrict__ out, float scale) {
  __shared__ __align__(16) short As[2][4096];  // Vt 128x32
  __shared__ __align__(16) short Bs[2][4096];  // P  128x32
  // XCD remap: one batch z per XCD. 512 = 8*64.
  const int id = blockIdx.x + blockIdx.y * 4 + blockIdx.z * 64;
  const int swz = (id & 7) * 64 + (id >> 3);
  const int z = swz >> 6;
  const int d0 = (swz & 3) * 128;
  const int n0 = ((swz >> 2) & 15) * 128;
  const short* __restrict__ A = Vt + (size_t)z * 1048576;  // [512][2048]
  const short* __restrict__ B = Pm + (size_t)z * 4194304;  // [2048][2048]
  const int t = threadIdx.x;
  const int lane = t & 63, w = t >> 6;
  const int aw = (w >> 1) * 64, bw = (w & 1) * 64;
  const int fr = lane & 15, l4 = lane >> 4;
  const int r0 = t >> 2, cs = t & 3;
  const int csw = (cs ^ ((r0 >> 1) & 3)) * 8;
  const short* pA = A + (size_t)(d0 + r0) * 2048 + csw;
  const short* pB = B + (size_t)(n0 + r0) * 2048 + csw;

#define PV_STG(buf, kt) do { \
    GLDS(pA + (kt) * 32, &As[(buf)][t * 8]); \
    GLDS(pA + (size_t)64 * 2048 + (kt) * 32, &As[(buf)][2048 + t * 8]); \
    GLDS(pB + (kt) * 32, &Bs[(buf)][t * 8]); \
    GLDS(pB + (size_t)64 * 2048 + (kt) * 32, &Bs[(buf)][2048 + t * 8]); \
  } while (0)

  f32x4 acc[4][4] = {};
  bf16x8 a[4], b[4];

  PV_STG(0, 0); PV_STG(1, 1);   // T0, T1 in flight (8 loads)

#pragma unroll 1
  for (int kt = 0; kt < 64; ++kt) {
    const int c = kt & 1;
    if (kt >= 1 && kt < 63) PV_STG(c ^ 1, kt + 1);
    if (kt < 63) { VMW(4); } else { VMW(0); }   // T(kt) landed in LDS
    SBAR();
#pragma unroll
    for (int i = 0; i < 4; ++i) a[i] = ldfrag32(&As[c][0], aw + i * 16 + fr, l4);
#pragma unroll
    for (int n = 0; n < 4; ++n) b[n] = ldfrag32(&Bs[c][0], bw + n * 16 + fr, l4);
    LGKM0_SB(); PRIO1();
#pragma unroll
    for (int i = 0; i < 4; ++i)
#pragma unroll
      for (int n = 0; n < 4; ++n)
        acc[i][n] = __builtin_amdgcn_mfma_f32_16x16x32_bf16(a[i], b[n], acc[i][n], 0, 0, 0);
    PRIO0(); SBAR();
  }
#undef PV_STG

  // epilogue: out = resid + acc * (scale / l[q])
  float linv[4];
#pragma unroll
  for (int n = 0; n < 4; ++n) {
    const int q = n0 + bw + n * 16 + fr;
    linv[n] = scale / l[z * 2048 + q];
  }
#pragma unroll
  for (int n = 0; n < 4; ++n) {
    const int q = n0 + bw + n * 16 + fr;
#pragma unroll
    for (int i = 0; i < 4; ++i) {
      const int d = d0 + aw + i * 16 + l4 * 4;
      const size_t idx = (size_t)z * 1048576 + (size_t)q * 512 + d;
      float4 rv = *(const float4*)(resid + idx);
      float4 o = { rv.x + acc[i][n][0] * linv[n], rv.y + acc[i][n][1] * linv[n],
                   rv.z + acc[i][n][2] * linv[n], rv.w + acc[i][n][3] * linv[n] };
      *(float4*)(out + idx) = o;
    }
  }
}

extern "C" void kernel_launch(void* const* d_in, const int* in_sizes, int n_in,
                              void* d_out, int out_size, void* d_ws, size_t ws_size,
                              hipStream_t stream) {
  const float* feature = (const float*)d_in[0];
  const float* wq = (const float*)d_in[1];
  const float* bq = (const float*)d_in[2];
  const float* wk = (const float*)d_in[3];
  const float* bk = (const float*)d_in[4];
  const float* wv = (const float*)d_in[5];
  const float* bv = (const float*)d_in[6];
  float* out = (float*)d_out;

  const size_t MN = (size_t)16384 * 512;
  short* Xb = (short*)d_ws;       // MN
  short* Wb = Xb + MN;            // 3 * 262144
  short* Q = Wb + 786432;         // MN (K follows contiguously)
  short* K = Q + MN;
  short* Vt = K + MN;             // [8][512][2048]
  short* P = Vt + MN;             // [8][2048][2048] unnormalized exp
  float* biasP = (float*)(P + (size_t)8 * 2048 * 2048);  // [3][512]
  float* l = biasP + 1536;        // [8*2048] row sums of exp

  prep<<<8968, 256, 0, stream>>>(feature, wq, wk, wv, bq, bk, bv, Xb, Wb, biasP, l);

  gemm_qkv<<<dim3(4, 128, 3), 256, 0, stream>>>(Xb, Wb, biasP, Q, Vt);
  gemm_qk8<<<dim3(16, 16, 8), 256, 0, stream>>>(Q, K, P, l);

  const float iscl = 0.044194173824159216f;  // 1/sqrt(512)
  gemm_pv8<<<dim3(4, 16, 8), 256, 0, stream>>>(P, Vt, l, feature, out, iscl);
}